// Round 1
// baseline (572.349 us; speedup 1.0000x reference)
//
#include <hip/hip_runtime.h>
#include <math.h>

// ContrastiveLoss fused kernel, round 0: correctness-first fp32 VALU version.
// B=4096, D=512, F=128. Fuses S = (E E^T)/0.1 and T = fn fn^T with BCE
// epilogue + per-row reductions; never materializes the 4096x4096 matrices.

constexpr int Bn = 4096;
constexpr int Dd = 512;
constexpr int Ff = 128;

__global__ __launch_bounds__(256) void zero_ws_kernel(float* __restrict__ row_sum,
                                                      int* __restrict__ pos_cnt) {
    int i = blockIdx.x * 256 + threadIdx.x;
    if (i < Bn) {
        row_sum[i] = 0.0f;
        pos_cnt[i] = 0;
    }
}

// One 64-lane wave per row; 4 rows per 256-thread block.
__global__ __launch_bounds__(256) void normalize_kernel(const float* __restrict__ sf,
                                                        float* __restrict__ fn) {
    int row = blockIdx.x * 4 + (threadIdx.x >> 6);
    int lane = threadIdx.x & 63;
    const float2 v = *reinterpret_cast<const float2*>(&sf[(size_t)row * Ff + lane * 2]);
    float ss = v.x * v.x + v.y * v.y;
    #pragma unroll
    for (int off = 32; off; off >>= 1) ss += __shfl_down(ss, off, 64);
    ss = __shfl(ss, 0, 64);  // broadcast
    float inv = 1.0f / fmaxf(sqrtf(ss), 1e-12f);
    float2 o;
    o.x = v.x * inv;
    o.y = v.y * inv;
    *reinterpret_cast<float2*>(&fn[(size_t)row * Ff + lane * 2]) = o;
}

// 64x64 output tile per 256-thread block; each thread owns a 4x4 micro-tile.
// Two K-phases: E (K=512) into accS, normalized features (K=128) into accT.
__global__ __launch_bounds__(256) void fused_tile_kernel(const float* __restrict__ E,
                                                         const float* __restrict__ FN,
                                                         float* __restrict__ row_sum,
                                                         int* __restrict__ pos_cnt) {
    __shared__ float As[64][33];  // +1 pad: compute-phase reads conflict-free
    __shared__ float Bs[64][33];

    const int tid = threadIdx.x;
    const int tx = tid & 15;
    const int ty = tid >> 4;
    const int ti = blockIdx.y * 64;
    const int tj = blockIdx.x * 64;

    float accS[4][4] = {};
    float accT[4][4] = {};

    // ---- Phase 1: E @ E^T, K = 512 in chunks of 32 ----
    for (int k0 = 0; k0 < Dd; k0 += 32) {
        __syncthreads();
        #pragma unroll
        for (int it = 0; it < 2; ++it) {
            int idx = tid + it * 256;   // 0..511 covers 64 rows x 8 float4
            int r = idx >> 3;
            int q = idx & 7;
            float4 va = *reinterpret_cast<const float4*>(
                &E[(size_t)(ti + r) * Dd + k0 + q * 4]);
            As[r][q * 4 + 0] = va.x; As[r][q * 4 + 1] = va.y;
            As[r][q * 4 + 2] = va.z; As[r][q * 4 + 3] = va.w;
            float4 vb = *reinterpret_cast<const float4*>(
                &E[(size_t)(tj + r) * Dd + k0 + q * 4]);
            Bs[r][q * 4 + 0] = vb.x; Bs[r][q * 4 + 1] = vb.y;
            Bs[r][q * 4 + 2] = vb.z; Bs[r][q * 4 + 3] = vb.w;
        }
        __syncthreads();
        #pragma unroll
        for (int kk = 0; kk < 32; ++kk) {
            float a[4], b[4];
            #pragma unroll
            for (int m = 0; m < 4; ++m) a[m] = As[ty * 4 + m][kk];
            #pragma unroll
            for (int n = 0; n < 4; ++n) b[n] = Bs[tx * 4 + n][kk];
            #pragma unroll
            for (int m = 0; m < 4; ++m)
                #pragma unroll
                for (int n = 0; n < 4; ++n)
                    accS[m][n] = fmaf(a[m], b[n], accS[m][n]);
        }
    }

    // ---- Phase 2: FN @ FN^T, K = 128 in chunks of 32 ----
    for (int k0 = 0; k0 < Ff; k0 += 32) {
        __syncthreads();
        #pragma unroll
        for (int it = 0; it < 2; ++it) {
            int idx = tid + it * 256;
            int r = idx >> 3;
            int q = idx & 7;
            float4 va = *reinterpret_cast<const float4*>(
                &FN[(size_t)(ti + r) * Ff + k0 + q * 4]);
            As[r][q * 4 + 0] = va.x; As[r][q * 4 + 1] = va.y;
            As[r][q * 4 + 2] = va.z; As[r][q * 4 + 3] = va.w;
            float4 vb = *reinterpret_cast<const float4*>(
                &FN[(size_t)(tj + r) * Ff + k0 + q * 4]);
            Bs[r][q * 4 + 0] = vb.x; Bs[r][q * 4 + 1] = vb.y;
            Bs[r][q * 4 + 2] = vb.z; Bs[r][q * 4 + 3] = vb.w;
        }
        __syncthreads();
        #pragma unroll
        for (int kk = 0; kk < 32; ++kk) {
            float a[4], b[4];
            #pragma unroll
            for (int m = 0; m < 4; ++m) a[m] = As[ty * 4 + m][kk];
            #pragma unroll
            for (int n = 0; n < 4; ++n) b[n] = Bs[tx * 4 + n][kk];
            #pragma unroll
            for (int m = 0; m < 4; ++m)
                #pragma unroll
                for (int n = 0; n < 4; ++n)
                    accT[m][n] = fmaf(a[m], b[n], accT[m][n]);
        }
    }

    // ---- Epilogue: BCE + per-row partials ----
    float rsum[4] = {0.0f, 0.0f, 0.0f, 0.0f};
    int pcnt[4] = {0, 0, 0, 0};
    #pragma unroll
    for (int m = 0; m < 4; ++m) {
        int gi = ti + ty * 4 + m;
        #pragma unroll
        for (int n = 0; n < 4; ++n) {
            int gj = tj + tx * 4 + n;
            if (gi != gj) {
                float S = accS[m][n] * 10.0f;           // /TEMPERATURE
                bool pos = accT[m][n] > 0.5f;           // THRESHOLD
                float x = pos ? -S : S;
                // softplus(x) = max(x,0) + log1p(exp(-|x|))  (matches jax.nn.softplus)
                float sp = fmaxf(x, 0.0f) + log1pf(expf(-fabsf(x)));
                rsum[m] += sp;
                pcnt[m] += pos ? 1 : 0;
            }
        }
    }

    // Reduce across the 16 tx lanes (contiguous within the wave).
    #pragma unroll
    for (int m = 0; m < 4; ++m) {
        #pragma unroll
        for (int off = 8; off; off >>= 1) {
            rsum[m] += __shfl_down(rsum[m], off, 16);
            pcnt[m] += __shfl_down(pcnt[m], off, 16);
        }
    }
    if (tx == 0) {
        #pragma unroll
        for (int m = 0; m < 4; ++m) {
            atomicAdd(&row_sum[ti + ty * 4 + m], rsum[m]);
            atomicAdd(&pos_cnt[ti + ty * 4 + m], pcnt[m]);
        }
    }
}

__global__ __launch_bounds__(256) void finalize_kernel(const float* __restrict__ row_sum,
                                                       const int* __restrict__ pos_cnt,
                                                       float* __restrict__ out) {
    __shared__ float ssum[256];
    __shared__ int scnt[256];
    float ls = 0.0f;
    int lc = 0;
    for (int r = threadIdx.x; r < Bn; r += 256) {
        int p = pos_cnt[r];
        if (p > 0 && p < Bn - 1) {  // >=1 positive AND >=1 negative
            ls += row_sum[r] / (float)(Bn - 1);
            lc += 1;
        }
    }
    ssum[threadIdx.x] = ls;
    scnt[threadIdx.x] = lc;
    __syncthreads();
    for (int s = 128; s; s >>= 1) {
        if (threadIdx.x < s) {
            ssum[threadIdx.x] += ssum[threadIdx.x + s];
            scnt[threadIdx.x] += scnt[threadIdx.x + s];
        }
        __syncthreads();
    }
    if (threadIdx.x == 0) {
        float nv = fmaxf((float)scnt[0], 1.0f);
        out[0] = ssum[0] / nv;
    }
}

extern "C" void kernel_launch(void* const* d_in, const int* in_sizes, int n_in,
                              void* d_out, int out_size, void* d_ws, size_t ws_size,
                              hipStream_t stream) {
    const float* E = (const float*)d_in[0];   // embeddings [4096,512] f32
    const float* SF = (const float*)d_in[1];  // similarity_features [4096,128] f32
    float* out = (float*)d_out;               // scalar f32 loss

    // Workspace layout: fn[4096*128] | row_sum[4096] | pos_cnt[4096]  (~2.1 MB)
    float* fn = (float*)d_ws;
    float* row_sum = fn + (size_t)Bn * Ff;
    int* pos_cnt = (int*)(row_sum + Bn);

    zero_ws_kernel<<<(Bn + 255) / 256, 256, 0, stream>>>(row_sum, pos_cnt);
    normalize_kernel<<<Bn / 4, 256, 0, stream>>>(SF, fn);
    dim3 grid(Bn / 64, Bn / 64);
    fused_tile_kernel<<<grid, 256, 0, stream>>>(E, fn, row_sum, pos_cnt);
    finalize_kernel<<<1, 256, 0, stream>>>(row_sum, pos_cnt, out);
}

// Round 2
// 174.625 us; speedup vs baseline: 3.2776x; 3.2776x over previous
//
#include <hip/hip_runtime.h>
#include <math.h>

// ContrastiveLoss round 1: bf16 hi/lo-split MFMA, triangular tiling.
// S = (E E^T)/0.1 and T = fn fn^T via 3-pass split (hh + hl + lh), fused BCE
// epilogue with per-row sums scattered to rows AND cols (symmetric matrices).

constexpr int Bn = 4096;
constexpr int Dd = 512;
constexpr int Ff = 128;

typedef __attribute__((ext_vector_type(8))) short bf16x8;
typedef __attribute__((ext_vector_type(4))) float f32x4;

__device__ __forceinline__ ushort f32_to_bf16(float x) {
    unsigned u = __float_as_uint(x);
    unsigned r = (u + 0x7FFFu + ((u >> 16) & 1u)) >> 16;  // RTNE
    return (ushort)r;
}
__device__ __forceinline__ float bf16_to_f32(ushort h) {
    return __uint_as_float(((unsigned)h) << 16);
}

__global__ __launch_bounds__(256) void zero_ws_kernel(float* __restrict__ row_sum,
                                                      int* __restrict__ pos_cnt) {
    int i = blockIdx.x * 256 + threadIdx.x;
    if (i < Bn) { row_sum[i] = 0.0f; pos_cnt[i] = 0; }
}

// Split embeddings into bf16 hi/lo. 4 elems/thread, vectorized.
__global__ __launch_bounds__(256) void split_E_kernel(const float* __restrict__ E,
                                                      ushort* __restrict__ eh,
                                                      ushort* __restrict__ el) {
    size_t i = (size_t)(blockIdx.x * 256 + threadIdx.x) * 4;
    float4 v = *reinterpret_cast<const float4*>(&E[i]);
    float c[4] = {v.x, v.y, v.z, v.w};
    ushort4 h, l;
    ushort hu[4], lu[4];
    #pragma unroll
    for (int j = 0; j < 4; ++j) {
        hu[j] = f32_to_bf16(c[j]);
        lu[j] = f32_to_bf16(c[j] - bf16_to_f32(hu[j]));
    }
    h.x = hu[0]; h.y = hu[1]; h.z = hu[2]; h.w = hu[3];
    l.x = lu[0]; l.y = lu[1]; l.z = lu[2]; l.w = lu[3];
    *reinterpret_cast<ushort4*>(&eh[i]) = h;
    *reinterpret_cast<ushort4*>(&el[i]) = l;
}

// L2-normalize similarity features and split into bf16 hi/lo.
// One 64-lane wave per row (F=128 -> 2 floats/lane); 4 rows per block.
__global__ __launch_bounds__(256) void normalize_split_F(const float* __restrict__ sf,
                                                         ushort* __restrict__ fh,
                                                         ushort* __restrict__ fl) {
    int row = blockIdx.x * 4 + (threadIdx.x >> 6);
    int lane = threadIdx.x & 63;
    const float2 v = *reinterpret_cast<const float2*>(&sf[(size_t)row * Ff + lane * 2]);
    float ss = v.x * v.x + v.y * v.y;
    #pragma unroll
    for (int off = 32; off; off >>= 1) ss += __shfl_xor(ss, off, 64);
    float inv = 1.0f / fmaxf(sqrtf(ss), 1e-12f);
    float fx = v.x * inv, fy = v.y * inv;
    ushort hx = f32_to_bf16(fx), hy = f32_to_bf16(fy);
    ushort lx = f32_to_bf16(fx - bf16_to_f32(hx));
    ushort ly = f32_to_bf16(fy - bf16_to_f32(hy));
    ushort2 h; h.x = hx; h.y = hy;
    ushort2 l; l.x = lx; l.y = ly;
    *reinterpret_cast<ushort2*>(&fh[(size_t)row * Ff + lane * 2]) = h;
    *reinterpret_cast<ushort2*>(&fl[(size_t)row * Ff + lane * 2]) = l;
}

// Stage a 128x64 bf16 tile (16 KB) via global_load_lds width 16.
// LDS dest linear; global SOURCE pre-swizzled (rule #21): stored byte b holds
// logical col (b%128) ^ ((row&7)<<4). Reads apply the same XOR -> ~2-way max.
__device__ __forceinline__ void stage_tile(const ushort* __restrict__ src, int stride,
                                           int k0, char* tile, int wave, int lane) {
    #pragma unroll
    for (int q = 0; q < 4; ++q) {
        int boff = wave * 4096 + q * 1024 + lane * 16;
        int row = boff >> 7;                       // 128 B per row
        int cb = (boff & 127) ^ ((row & 7) << 4);  // logical col byte
        const ushort* g = src + (size_t)row * stride + k0 + (cb >> 1);
        __builtin_amdgcn_global_load_lds(
            (const __attribute__((address_space(1))) void*)g,
            (__attribute__((address_space(3))) void*)(tile + wave * 4096 + q * 1024),
            16, 0, 0);
    }
}

__device__ __forceinline__ void mfma_step(f32x4 (&acc)[4][4], const char* At, const char* Bt,
                                          int wrow, int wcol, int lane) {
    #pragma unroll
    for (int ks = 0; ks < 2; ++ks) {
        bf16x8 a[4], b[4];
        int koff = ks * 64 + ((lane >> 4) << 4);   // byte offset of this lane's K-octet
        #pragma unroll
        for (int m = 0; m < 4; ++m) {
            int row = wrow + m * 16 + (lane & 15);
            a[m] = *reinterpret_cast<const bf16x8*>(At + row * 128 + (koff ^ ((row & 7) << 4)));
        }
        #pragma unroll
        for (int n = 0; n < 4; ++n) {
            int row = wcol + n * 16 + (lane & 15);
            b[n] = *reinterpret_cast<const bf16x8*>(Bt + row * 128 + (koff ^ ((row & 7) << 4)));
        }
        #pragma unroll
        for (int m = 0; m < 4; ++m)
            #pragma unroll
            for (int n = 0; n < 4; ++n)
                acc[m][n] = __builtin_amdgcn_mfma_f32_16x16x32_bf16(a[m], b[n], acc[m][n], 0, 0, 0);
    }
}

__device__ __forceinline__ void gemm_pass(f32x4 (&acc)[4][4],
                                          const ushort* __restrict__ Abase,
                                          const ushort* __restrict__ Bbase,
                                          int stride, int K, char* At, char* Bt,
                                          int wave, int lane, int wrow, int wcol) {
    for (int k0 = 0; k0 < K; k0 += 64) {
        stage_tile(Abase, stride, k0, At, wave, lane);
        stage_tile(Bbase, stride, k0, Bt, wave, lane);
        __syncthreads();   // drains vmcnt -> LDS tiles complete
        mfma_step(acc, At, Bt, wrow, wcol, lane);
        __syncthreads();   // all reads done before next overwrite
    }
}

// One 128x128 tile per 256-thread block, lower-triangle blocks only.
// 4 waves in 2x2; each wave: 64x64 via 4x4 frags of mfma_f32_16x16x32_bf16.
__global__ __launch_bounds__(256) void fused_mfma_kernel(
    const ushort* __restrict__ Eh, const ushort* __restrict__ El,
    const ushort* __restrict__ Fh, const ushort* __restrict__ Fl,
    float* __restrict__ row_sum, int* __restrict__ pos_cnt) {
    __shared__ __align__(16) char smem[32768];
    char* At = smem;
    char* Bt = smem + 16384;

    // Linear block id -> lower-triangle (bi, bj), bi >= bj.
    int p = blockIdx.x;
    int bi = (int)((sqrtf(8.0f * (float)p + 1.0f) - 1.0f) * 0.5f);
    while ((bi + 1) * (bi + 2) / 2 <= p) ++bi;
    while (bi * (bi + 1) / 2 > p) --bi;
    int bj = p - bi * (bi + 1) / 2;

    const int ti = bi * 128, tj = bj * 128;
    const int tid = threadIdx.x;
    const int lane = tid & 63;
    const int wave = tid >> 6;
    const int wrow = (wave >> 1) * 64;
    const int wcol = (wave & 1) * 64;

    f32x4 acc[4][4];
    const f32x4 z4 = {0.0f, 0.0f, 0.0f, 0.0f};
    #pragma unroll
    for (int m = 0; m < 4; ++m)
        #pragma unroll
        for (int n = 0; n < 4; ++n) acc[m][n] = z4;

    // ---- T = fn fn^T: hh + hl + lh ----
    gemm_pass(acc, Fh + (size_t)ti * Ff, Fh + (size_t)tj * Ff, Ff, Ff, At, Bt, wave, lane, wrow, wcol);
    gemm_pass(acc, Fh + (size_t)ti * Ff, Fl + (size_t)tj * Ff, Ff, Ff, At, Bt, wave, lane, wrow, wcol);
    gemm_pass(acc, Fl + (size_t)ti * Ff, Fh + (size_t)tj * Ff, Ff, Ff, At, Bt, wave, lane, wrow, wcol);

    // Collapse T into a positive-decision bitmask; free the accumulator.
    unsigned long long pmask = 0;
    #pragma unroll
    for (int m = 0; m < 4; ++m)
        #pragma unroll
        for (int n = 0; n < 4; ++n)
            #pragma unroll
            for (int r = 0; r < 4; ++r)
                if (acc[m][n][r] > 0.5f) pmask |= 1ull << (m * 16 + n * 4 + r);

    #pragma unroll
    for (int m = 0; m < 4; ++m)
        #pragma unroll
        for (int n = 0; n < 4; ++n) acc[m][n] = z4;

    // ---- S_raw = E E^T: hh + hl + lh ----
    gemm_pass(acc, Eh + (size_t)ti * Dd, Eh + (size_t)tj * Dd, Dd, Dd, At, Bt, wave, lane, wrow, wcol);
    gemm_pass(acc, Eh + (size_t)ti * Dd, El + (size_t)tj * Dd, Dd, Dd, At, Bt, wave, lane, wrow, wcol);
    gemm_pass(acc, El + (size_t)ti * Dd, Eh + (size_t)tj * Dd, Dd, Dd, At, Bt, wave, lane, wrow, wcol);

    // ---- BCE epilogue. C/D layout: col = lane&15, row = (lane>>4)*4 + r. ----
    float rowS[4][4]; int rowC[4][4];
    float colS[4] = {0, 0, 0, 0}; int colC[4] = {0, 0, 0, 0};
    #pragma unroll
    for (int m = 0; m < 4; ++m) {
        #pragma unroll
        for (int r = 0; r < 4; ++r) {
            float s = 0.0f; int c = 0;
            int gi = ti + wrow + m * 16 + ((lane >> 4) << 2) + r;
            #pragma unroll
            for (int n = 0; n < 4; ++n) {
                int gj = tj + wcol + n * 16 + (lane & 15);
                if (gi != gj) {
                    float S = acc[m][n][r] * 10.0f;             // /TEMPERATURE
                    bool pos = (pmask >> (m * 16 + n * 4 + r)) & 1;
                    float x = pos ? -S : S;
                    float sp = fmaxf(x, 0.0f) + log1pf(expf(-fabsf(x)));  // softplus
                    s += sp;
                    c += pos ? 1 : 0;
                    if (bi != bj) { colS[n] += sp; colC[n] += pos ? 1 : 0; }
                }
            }
            rowS[m][r] = s; rowC[m][r] = c;
        }
    }
    // Row sums: reduce over the 16 col-lanes (lane&15).
    #pragma unroll
    for (int m = 0; m < 4; ++m)
        #pragma unroll
        for (int r = 0; r < 4; ++r) {
            float s = rowS[m][r]; int c = rowC[m][r];
            #pragma unroll
            for (int off = 8; off; off >>= 1) {
                s += __shfl_xor(s, off, 16);
                c += __shfl_xor(c, off, 16);
            }
            if ((lane & 15) == 0) {
                int gi = ti + wrow + m * 16 + ((lane >> 4) << 2) + r;
                atomicAdd(&row_sum[gi], s);
                atomicAdd(&pos_cnt[gi], c);
            }
        }
    // Mirror: column sums become row sums of the transposed tile (symmetry).
    if (bi != bj) {
        #pragma unroll
        for (int n = 0; n < 4; ++n) {
            float s = colS[n]; int c = colC[n];
            s += __shfl_xor(s, 16, 64); c += __shfl_xor(c, 16, 64);
            s += __shfl_xor(s, 32, 64); c += __shfl_xor(c, 32, 64);
            if ((lane >> 4) == 0) {
                int gj = tj + wcol + n * 16 + (lane & 15);
                atomicAdd(&row_sum[gj], s);
                atomicAdd(&pos_cnt[gj], c);
            }
        }
    }
}

__global__ __launch_bounds__(256) void finalize_kernel(const float* __restrict__ row_sum,
                                                       const int* __restrict__ pos_cnt,
                                                       float* __restrict__ out) {
    __shared__ float ssum[256];
    __shared__ int scnt[256];
    float ls = 0.0f;
    int lc = 0;
    for (int r = threadIdx.x; r < Bn; r += 256) {
        int pz = pos_cnt[r];
        if (pz > 0 && pz < Bn - 1) {   // >=1 positive AND >=1 negative
            ls += row_sum[r] / (float)(Bn - 1);
            lc += 1;
        }
    }
    ssum[threadIdx.x] = ls;
    scnt[threadIdx.x] = lc;
    __syncthreads();
    for (int s = 128; s; s >>= 1) {
        if (threadIdx.x < s) {
            ssum[threadIdx.x] += ssum[threadIdx.x + s];
            scnt[threadIdx.x] += scnt[threadIdx.x + s];
        }
        __syncthreads();
    }
    if (threadIdx.x == 0) {
        float nv = fmaxf((float)scnt[0], 1.0f);
        out[0] = ssum[0] / nv;
    }
}

extern "C" void kernel_launch(void* const* d_in, const int* in_sizes, int n_in,
                              void* d_out, int out_size, void* d_ws, size_t ws_size,
                              hipStream_t stream) {
    const float* E = (const float*)d_in[0];   // [4096,512] f32
    const float* SF = (const float*)d_in[1];  // [4096,128] f32
    float* out = (float*)d_out;

    // ws: eh(4MB) | el(4MB) | fh(1MB) | fl(1MB) | row_sum(16KB) | pos_cnt(16KB)
    ushort* eh = (ushort*)d_ws;
    ushort* el = eh + (size_t)Bn * Dd;
    ushort* fh = el + (size_t)Bn * Dd;
    ushort* fl = fh + (size_t)Bn * Ff;
    float* row_sum = (float*)(fl + (size_t)Bn * Ff);
    int* pos_cnt = (int*)(row_sum + Bn);

    zero_ws_kernel<<<Bn / 256, 256, 0, stream>>>(row_sum, pos_cnt);
    split_E_kernel<<<(Bn * Dd / 4) / 256, 256, 0, stream>>>(E, eh, el);
    normalize_split_F<<<Bn / 4, 256, 0, stream>>>(SF, fh, fl);
    int nblocks = (Bn / 128) * (Bn / 128 + 1) / 2;   // 528 lower-triangle tiles
    fused_mfma_kernel<<<nblocks, 256, 0, stream>>>(eh, el, fh, fl, row_sum, pos_cnt);
    finalize_kernel<<<1, 256, 0, stream>>>(row_sum, pos_cnt, out);
}

// Round 3
// 94.364 us; speedup vs baseline: 6.0653x; 1.8505x over previous
//
#include <hip/hip_runtime.h>
#include <math.h>

// ContrastiveLoss round 2: T-first with data-dependent S skip + fused hi/lo staging.
// T = fn fn^T decides pos/valid (K=128, cheap). S = E E^T (K=512) only affects the
// loss through rows that are valid; the S kernel exits per-block unless its row- or
// col-block contains a valid row. Exact same function for any input.

constexpr int Bn = 4096;
constexpr int Dd = 512;
constexpr int Ff = 128;

typedef __attribute__((ext_vector_type(8))) short bf16x8;
typedef __attribute__((ext_vector_type(4))) float f32x4;

__device__ __forceinline__ ushort f32_to_bf16(float x) {
    unsigned u = __float_as_uint(x);
    unsigned r = (u + 0x7FFFu + ((u >> 16) & 1u)) >> 16;  // RTNE
    return (ushort)r;
}
__device__ __forceinline__ float bf16_to_f32(ushort h) {
    return __uint_as_float(((unsigned)h) << 16);
}

__global__ __launch_bounds__(256) void zero_ws_kernel(float* __restrict__ row_sum,
                                                      int* __restrict__ pos_cnt,
                                                      int* __restrict__ rb_any) {
    int i = blockIdx.x * 256 + threadIdx.x;
    if (i < Bn) { row_sum[i] = 0.0f; pos_cnt[i] = 0; }
    if (i < Bn / 128) rb_any[i] = 0;
}

__global__ __launch_bounds__(256) void split_E_kernel(const float* __restrict__ E,
                                                      ushort* __restrict__ eh,
                                                      ushort* __restrict__ el) {
    size_t i = (size_t)(blockIdx.x * 256 + threadIdx.x) * 4;
    float4 v = *reinterpret_cast<const float4*>(&E[i]);
    float c[4] = {v.x, v.y, v.z, v.w};
    ushort4 h, l;
    ushort hu[4], lu[4];
    #pragma unroll
    for (int j = 0; j < 4; ++j) {
        hu[j] = f32_to_bf16(c[j]);
        lu[j] = f32_to_bf16(c[j] - bf16_to_f32(hu[j]));
    }
    h.x = hu[0]; h.y = hu[1]; h.z = hu[2]; h.w = hu[3];
    l.x = lu[0]; l.y = lu[1]; l.z = lu[2]; l.w = lu[3];
    *reinterpret_cast<ushort4*>(&eh[i]) = h;
    *reinterpret_cast<ushort4*>(&el[i]) = l;
}

__global__ __launch_bounds__(256) void normalize_split_F(const float* __restrict__ sf,
                                                         ushort* __restrict__ fh,
                                                         ushort* __restrict__ fl) {
    int row = blockIdx.x * 4 + (threadIdx.x >> 6);
    int lane = threadIdx.x & 63;
    const float2 v = *reinterpret_cast<const float2*>(&sf[(size_t)row * Ff + lane * 2]);
    float ss = v.x * v.x + v.y * v.y;
    #pragma unroll
    for (int off = 32; off; off >>= 1) ss += __shfl_xor(ss, off, 64);
    float inv = 1.0f / fmaxf(sqrtf(ss), 1e-12f);
    float fx = v.x * inv, fy = v.y * inv;
    ushort hx = f32_to_bf16(fx), hy = f32_to_bf16(fy);
    ushort lx = f32_to_bf16(fx - bf16_to_f32(hx));
    ushort ly = f32_to_bf16(fy - bf16_to_f32(hy));
    ushort2 h; h.x = hx; h.y = hy;
    ushort2 l; l.x = lx; l.y = ly;
    *reinterpret_cast<ushort2*>(&fh[(size_t)row * Ff + lane * 2]) = h;
    *reinterpret_cast<ushort2*>(&fl[(size_t)row * Ff + lane * 2]) = l;
}

// Stage a 128x64 bf16 tile (16 KB) via global_load_lds width 16.
// LDS dest linear; global SOURCE pre-swizzled (rule #21); reads apply same XOR.
// Validated round 1: 0 bank conflicts, correct.
__device__ __forceinline__ void stage_tile(const ushort* __restrict__ src, int stride,
                                           int k0, char* tile, int wave, int lane) {
    #pragma unroll
    for (int q = 0; q < 4; ++q) {
        int boff = wave * 4096 + q * 1024 + lane * 16;
        int row = boff >> 7;                       // 128 B per row
        int cb = (boff & 127) ^ ((row & 7) << 4);  // logical col byte
        const ushort* g = src + (size_t)row * stride + k0 + (cb >> 1);
        __builtin_amdgcn_global_load_lds(
            (const __attribute__((address_space(1))) void*)g,
            (__attribute__((address_space(3))) void*)(tile + wave * 4096 + q * 1024),
            16, 0, 0);
    }
}

__device__ __forceinline__ void mfma_step(f32x4 (&acc)[4][4], const char* At, const char* Bt,
                                          int wrow, int wcol, int lane) {
    #pragma unroll
    for (int ks = 0; ks < 2; ++ks) {
        bf16x8 a[4], b[4];
        int koff = ks * 64 + ((lane >> 4) << 4);
        #pragma unroll
        for (int m = 0; m < 4; ++m) {
            int row = wrow + m * 16 + (lane & 15);
            a[m] = *reinterpret_cast<const bf16x8*>(At + row * 128 + (koff ^ ((row & 7) << 4)));
        }
        #pragma unroll
        for (int n = 0; n < 4; ++n) {
            int row = wcol + n * 16 + (lane & 15);
            b[n] = *reinterpret_cast<const bf16x8*>(Bt + row * 128 + (koff ^ ((row & 7) << 4)));
        }
        #pragma unroll
        for (int m = 0; m < 4; ++m)
            #pragma unroll
            for (int n = 0; n < 4; ++n)
                acc[m][n] = __builtin_amdgcn_mfma_f32_16x16x32_bf16(a[m], b[n], acc[m][n], 0, 0, 0);
    }
}

__device__ __forceinline__ void tri_decode(int p, int& bi, int& bj) {
    bi = (int)((sqrtf(8.0f * (float)p + 1.0f) - 1.0f) * 0.5f);
    while ((bi + 1) * (bi + 2) / 2 <= p) ++bi;
    while (bi * (bi + 1) / 2 > p) --bi;
    bj = p - bi * (bi + 1) / 2;
}

// T kernel: 128x128 lower-triangle tiles of fn fn^T via fused hh+hl+lh.
// Outputs: per-tile positive bitmask (2 KB/tile) + per-row positive counts.
__global__ __launch_bounds__(256) void t_kernel(const ushort* __restrict__ Fh,
                                                const ushort* __restrict__ Fl,
                                                unsigned long long* __restrict__ posbits,
                                                int* __restrict__ pos_cnt) {
    __shared__ __align__(16) char smem[65536];
    char* Ah = smem;
    char* Al = smem + 16384;
    char* Bh = smem + 32768;
    char* Bl = smem + 49152;

    int bi, bj; tri_decode(blockIdx.x, bi, bj);
    const int ti = bi * 128, tj = bj * 128;
    const int tid = threadIdx.x;
    const int lane = tid & 63;
    const int wave = tid >> 6;
    const int wrow = (wave >> 1) * 64;
    const int wcol = (wave & 1) * 64;

    f32x4 acc[4][4];
    const f32x4 z4 = {0.0f, 0.0f, 0.0f, 0.0f};
    #pragma unroll
    for (int m = 0; m < 4; ++m)
        #pragma unroll
        for (int n = 0; n < 4; ++n) acc[m][n] = z4;

    for (int k0 = 0; k0 < Ff; k0 += 64) {
        stage_tile(Fh + (size_t)ti * Ff, Ff, k0, Ah, wave, lane);
        stage_tile(Fl + (size_t)ti * Ff, Ff, k0, Al, wave, lane);
        stage_tile(Fh + (size_t)tj * Ff, Ff, k0, Bh, wave, lane);
        stage_tile(Fl + (size_t)tj * Ff, Ff, k0, Bl, wave, lane);
        __syncthreads();
        mfma_step(acc, Ah, Bh, wrow, wcol, lane);  // hh
        mfma_step(acc, Ah, Bl, wrow, wcol, lane);  // hl
        mfma_step(acc, Al, Bh, wrow, wcol, lane);  // lh
        __syncthreads();
    }

    // Positive bits (raw T > 0.5; diagonal gating applied by consumers).
    unsigned long long pm = 0;
    #pragma unroll
    for (int m = 0; m < 4; ++m)
        #pragma unroll
        for (int n = 0; n < 4; ++n)
            #pragma unroll
            for (int r = 0; r < 4; ++r)
                if (acc[m][n][r] > 0.5f) pm |= 1ull << (m * 16 + n * 4 + r);
    posbits[(size_t)blockIdx.x * 256 + tid] = pm;

    // Per-row positive counts (off-diagonal only), rows + mirrored cols.
    int colC[4] = {0, 0, 0, 0};
    #pragma unroll
    for (int m = 0; m < 4; ++m) {
        #pragma unroll
        for (int r = 0; r < 4; ++r) {
            int c = 0;
            int gi = ti + wrow + m * 16 + ((lane >> 4) << 2) + r;
            #pragma unroll
            for (int n = 0; n < 4; ++n) {
                int gj = tj + wcol + n * 16 + (lane & 15);
                bool pos = (pm >> (m * 16 + n * 4 + r)) & 1;
                if (gi != gj && pos) {
                    c += 1;
                    if (bi != bj) colC[n] += 1;
                }
            }
            #pragma unroll
            for (int off = 8; off; off >>= 1) c += __shfl_xor(c, off, 16);
            if ((lane & 15) == 0 && c) atomicAdd(&pos_cnt[gi], c);
        }
    }
    if (bi != bj) {
        #pragma unroll
        for (int n = 0; n < 4; ++n) {
            int c = colC[n];
            c += __shfl_xor(c, 16, 64);
            c += __shfl_xor(c, 32, 64);
            if ((lane >> 4) == 0 && c) {
                int gj = tj + wcol + n * 16 + (lane & 15);
                atomicAdd(&pos_cnt[gj], c);
            }
        }
    }
}

// valid[i] -> rowblock-any flags (128-row granularity).
__global__ __launch_bounds__(256) void flags_kernel(const int* __restrict__ pos_cnt,
                                                    int* __restrict__ rb_any) {
    int i = blockIdx.x * 256 + threadIdx.x;
    int pc = pos_cnt[i];
    if (pc > 0 && pc < Bn - 1) atomicOr(&rb_any[i >> 7], 1);
}

// S kernel: exits unless its row- or col-block has a valid row. When active,
// fused hh+hl+lh over K=512 with BCE epilogue using cached positive bits.
__global__ __launch_bounds__(256) void s_kernel(const ushort* __restrict__ Eh,
                                                const ushort* __restrict__ El,
                                                const unsigned long long* __restrict__ posbits,
                                                const int* __restrict__ rb_any,
                                                float* __restrict__ row_sum) {
    int bi, bj; tri_decode(blockIdx.x, bi, bj);
    if (!(rb_any[bi] | rb_any[bj])) return;   // no valid row touched by this tile

    __shared__ __align__(16) char smem[65536];
    char* Ah = smem;
    char* Al = smem + 16384;
    char* Bh = smem + 32768;
    char* Bl = smem + 49152;

    const int ti = bi * 128, tj = bj * 128;
    const int tid = threadIdx.x;
    const int lane = tid & 63;
    const int wave = tid >> 6;
    const int wrow = (wave >> 1) * 64;
    const int wcol = (wave & 1) * 64;

    f32x4 acc[4][4];
    const f32x4 z4 = {0.0f, 0.0f, 0.0f, 0.0f};
    #pragma unroll
    for (int m = 0; m < 4; ++m)
        #pragma unroll
        for (int n = 0; n < 4; ++n) acc[m][n] = z4;

    for (int k0 = 0; k0 < Dd; k0 += 64) {
        stage_tile(Eh + (size_t)ti * Dd, Dd, k0, Ah, wave, lane);
        stage_tile(El + (size_t)ti * Dd, Dd, k0, Al, wave, lane);
        stage_tile(Eh + (size_t)tj * Dd, Dd, k0, Bh, wave, lane);
        stage_tile(El + (size_t)tj * Dd, Dd, k0, Bl, wave, lane);
        __syncthreads();
        mfma_step(acc, Ah, Bh, wrow, wcol, lane);  // hh
        mfma_step(acc, Ah, Bl, wrow, wcol, lane);  // hl
        mfma_step(acc, Al, Bh, wrow, wcol, lane);  // lh
        __syncthreads();
    }

    unsigned long long pm = posbits[(size_t)blockIdx.x * 256 + tid];

    float colS[4] = {0, 0, 0, 0};
    #pragma unroll
    for (int m = 0; m < 4; ++m) {
        #pragma unroll
        for (int r = 0; r < 4; ++r) {
            float s = 0.0f;
            int gi = ti + wrow + m * 16 + ((lane >> 4) << 2) + r;
            #pragma unroll
            for (int n = 0; n < 4; ++n) {
                int gj = tj + wcol + n * 16 + (lane & 15);
                if (gi != gj) {
                    float S = acc[m][n][r] * 10.0f;            // /TEMPERATURE
                    bool pos = (pm >> (m * 16 + n * 4 + r)) & 1;
                    float x = pos ? -S : S;
                    float sp = fmaxf(x, 0.0f) + log1pf(expf(-fabsf(x)));  // softplus
                    s += sp;
                    if (bi != bj) colS[n] += sp;
                }
            }
            #pragma unroll
            for (int off = 8; off; off >>= 1) s += __shfl_xor(s, off, 16);
            if ((lane & 15) == 0) atomicAdd(&row_sum[gi], s);
        }
    }
    if (bi != bj) {
        #pragma unroll
        for (int n = 0; n < 4; ++n) {
            float s = colS[n];
            s += __shfl_xor(s, 16, 64);
            s += __shfl_xor(s, 32, 64);
            if ((lane >> 4) == 0) {
                int gj = tj + wcol + n * 16 + (lane & 15);
                atomicAdd(&row_sum[gj], s);
            }
        }
    }
}

__global__ __launch_bounds__(256) void finalize_kernel(const float* __restrict__ row_sum,
                                                       const int* __restrict__ pos_cnt,
                                                       float* __restrict__ out) {
    __shared__ float ssum[256];
    __shared__ int scnt[256];
    float ls = 0.0f;
    int lc = 0;
    for (int r = threadIdx.x; r < Bn; r += 256) {
        int pz = pos_cnt[r];
        if (pz > 0 && pz < Bn - 1) {   // >=1 positive AND >=1 negative
            ls += row_sum[r] / (float)(Bn - 1);
            lc += 1;
        }
    }
    ssum[threadIdx.x] = ls;
    scnt[threadIdx.x] = lc;
    __syncthreads();
    for (int s = 128; s; s >>= 1) {
        if (threadIdx.x < s) {
            ssum[threadIdx.x] += ssum[threadIdx.x + s];
            scnt[threadIdx.x] += scnt[threadIdx.x + s];
        }
        __syncthreads();
    }
    if (threadIdx.x == 0) {
        float nv = fmaxf((float)scnt[0], 1.0f);
        out[0] = ssum[0] / nv;
    }
}

extern "C" void kernel_launch(void* const* d_in, const int* in_sizes, int n_in,
                              void* d_out, int out_size, void* d_ws, size_t ws_size,
                              hipStream_t stream) {
    const float* E = (const float*)d_in[0];   // [4096,512] f32
    const float* SF = (const float*)d_in[1];  // [4096,128] f32
    float* out = (float*)d_out;

    constexpr int NT = (Bn / 128) * (Bn / 128 + 1) / 2;  // 528 triangle tiles

    // ws: eh(4M) el(4M) fh(1M) fl(1M) row_sum(16K) pos_cnt(16K) rb_any(128B) posbits(1.06M)
    ushort* eh = (ushort*)d_ws;
    ushort* el = eh + (size_t)Bn * Dd;
    ushort* fh = el + (size_t)Bn * Dd;
    ushort* fl = fh + (size_t)Bn * Ff;
    float* row_sum = (float*)(fl + (size_t)Bn * Ff);
    int* pos_cnt = (int*)(row_sum + Bn);
    int* rb_any = pos_cnt + Bn;
    unsigned long long* posbits = (unsigned long long*)(((size_t)(rb_any + 32) + 15) & ~15ull);

    zero_ws_kernel<<<Bn / 256, 256, 0, stream>>>(row_sum, pos_cnt, rb_any);
    split_E_kernel<<<(Bn * Dd / 4) / 256, 256, 0, stream>>>(E, eh, el);
    normalize_split_F<<<Bn / 4, 256, 0, stream>>>(SF, fh, fl);
    t_kernel<<<NT, 256, 0, stream>>>(fh, fl, posbits, pos_cnt);
    flags_kernel<<<Bn / 256, 256, 0, stream>>>(pos_cnt, rb_any);
    s_kernel<<<NT, 256, 0, stream>>>(eh, el, posbits, rb_any, row_sum);
    finalize_kernel<<<1, 256, 0, stream>>>(row_sum, pos_cnt, out);
}